// Round 1
// baseline (2289.832 us; speedup 1.0000x reference)
//
#include <hip/hip_runtime.h>

#define KDIM 50
#define TDIM 40
#define VDIM 30000
#define THDIM 800
#define EHDIM 200
#define EDIM 300
#define BDIM 100
#define DELTAF 0.005f
#define EPSF 1e-6f
#define LOGD (-5.2983174f)
#define MROWS 2560   // TDIM*64 rows for MFMA A operand
#define KPAD 320     // E padded to 320
#define VT 80        // v-tile per MFMA block
#define NBLK_V 375   // 30000/80
#define LBSTR 328    // LDS B-tile row stride (bf16 elems), +8 pad for banks

typedef __attribute__((ext_vector_type(8))) short bf16x8;
typedef __attribute__((ext_vector_type(4))) float f32x4;

__device__ inline float wred64(float v) {
  v += __shfl_xor(v, 32, 64); v += __shfl_xor(v, 16, 64);
  v += __shfl_xor(v, 8, 64);  v += __shfl_xor(v, 4, 64);
  v += __shfl_xor(v, 2, 64);  v += __shfl_xor(v, 1, 64);
  return v;
}

__device__ inline unsigned short f2bf(float f) {
  union { float f; unsigned u; } x; x.f = f;
  unsigned r = x.u + 0x7fffu + ((x.u >> 16) & 1u);
  return (unsigned short)(r >> 16);
}

// ---------------- A2 prep: mu_q_alpha[k][t][e] -> bf16 A2[t*64+k][e<320] ----
__global__ void k_prep_A2(const float* __restrict__ mu_q, unsigned short* __restrict__ A2) {
  int idx = blockIdx.x * 256 + threadIdx.x;   // 2560*320 = 819200
  if (idx >= MROWS * KPAD) return;
  int m = idx / KPAD, e = idx % KPAD;
  int t = m >> 6, kp = m & 63;
  float v = 0.f;
  if (kp < KDIM && e < EDIM) v = mu_q[(kp * TDIM + t) * EDIM + e];
  A2[idx] = f2bf(v);
}

// ---------------- out_map = rnn_inp @ W_map^T + b_map  [40,200] -------------
__global__ void k_map(const float* __restrict__ rnn, const float* __restrict__ Wmap,
                      const float* __restrict__ bmap, float* __restrict__ omap) {
  int ep = blockIdx.x, vc = blockIdx.y, tid = threadIdx.x;
  int e0 = ep * 2;
  const float4* W4 = (const float4*)Wmap;
  const float4* R4 = (const float4*)rnn;
  float acc0[TDIM], acc1[TDIM];
#pragma unroll
  for (int t = 0; t < TDIM; t++) { acc0[t] = 0.f; acc1[t] = 0.f; }
  int v4end = (vc + 1) * 1875;
  for (int v4 = vc * 1875 + tid; v4 < v4end; v4 += 256) {
    float4 wa = W4[e0 * 7500 + v4];
    float4 wb = W4[(e0 + 1) * 7500 + v4];
#pragma unroll
    for (int t = 0; t < TDIM; t++) {
      float4 r = R4[t * 7500 + v4];
      acc0[t] += wa.x * r.x + wa.y * r.y + wa.z * r.z + wa.w * r.w;
      acc1[t] += wb.x * r.x + wb.y * r.y + wb.z * r.z + wb.w * r.w;
    }
  }
  __shared__ float part[4][2][TDIM];
  int w = tid >> 6;
#pragma unroll
  for (int t = 0; t < TDIM; t++) {
    float a = wred64(acc0[t]);
    float b = wred64(acc1[t]);
    if ((tid & 63) == 0) { part[w][0][t] = a; part[w][1][t] = b; }
  }
  __syncthreads();
  if (tid < TDIM * 2) {
    int t = tid % TDIM, which = tid / TDIM;
    float s = part[0][which][t] + part[1][which][t] + part[2][which][t] + part[3][which][t];
    if (vc == 0) s += bmap[e0 + which];
    atomicAdd(&omap[t * EHDIM + e0 + which], s);
  }
}

// ---------------- Whh transpose+pack to bf16 pairs: WhhT[l][jp][i] ----------
__global__ void k_wt(const float* __restrict__ Whh, unsigned* __restrict__ WhhT) {
  int l = blockIdx.x / 100, jp = blockIdx.x % 100;
  for (int i = threadIdx.x; i < THDIM; i += 256) {
    float w0 = Whh[(l * THDIM + i) * EHDIM + 2 * jp];
    float w1 = Whh[(l * THDIM + i) * EHDIM + 2 * jp + 1];
    WhhT[(l * 100 + jp) * THDIM + i] = (unsigned)f2bf(w0) | ((unsigned)f2bf(w1) << 16);
  }
}

// ---------------- LSTM input GEMM: G[t][i] = Wih[l][i]·x[t] + bih + bhh -----
__global__ void k_igemm(const float* __restrict__ Wih, const float* __restrict__ bih,
                        const float* __restrict__ bhh, const float* __restrict__ x,
                        float* __restrict__ G, int l) {
  int wave = threadIdx.x >> 6, lane = threadIdx.x & 63;
  int d0 = blockIdx.x * 80 + wave * 20;
  for (int n = 0; n < 20; n++) {
    int d = d0 + n;
    int t = d / THDIM, i = d % THDIM;
    const float* row = Wih + (l * THDIM + i) * EHDIM;
    const float* xt = x + t * EHDIM;
    float acc = 0.f;
#pragma unroll
    for (int m = 0; m < 4; m++) { int j = m * 64 + lane; if (j < EHDIM) acc += row[j] * xt[j]; }
    acc = wred64(acc);
    if (lane == 0) G[t * THDIM + i] = acc + bih[l * THDIM + i] + bhh[l * THDIM + i];
  }
}

// ---------------- LSTM recurrence (single block, streams bf16 WhhT) ---------
__global__ __launch_bounds__(1024) void k_rec(const unsigned* __restrict__ WT,
                                              const float* __restrict__ G,
                                              float* __restrict__ xout) {
  __shared__ __align__(16) float h[EHDIM];
  __shared__ float g[THDIM];
  int tid = threadIdx.x;
  if (tid < EHDIM) h[tid] = 0.f;
  float c = 0.f;
  __syncthreads();
  for (int t = 0; t < TDIM; t++) {
    if (tid < THDIM) {
      float acc = G[t * THDIM + tid];
      const unsigned* wp = WT + tid;
      const float4* h4 = (const float4*)h;
      for (int q = 0; q < 50; q++) {
        float4 hq = h4[q];
        unsigned wa = wp[(2 * q) * THDIM];
        unsigned wb = wp[(2 * q + 1) * THDIM];
        union { unsigned u; float f; } la, ha, lb, hb;
        la.u = wa << 16; ha.u = wa & 0xffff0000u;
        lb.u = wb << 16; hb.u = wb & 0xffff0000u;
        acc += la.f * hq.x + ha.f * hq.y + lb.f * hq.z + hb.f * hq.w;
      }
      g[tid] = acc;
    }
    __syncthreads();
    if (tid < EHDIM) {
      float si = 1.f / (1.f + __expf(-g[tid]));
      float sf = 1.f / (1.f + __expf(-g[EHDIM * 1 + tid - EHDIM + 200]));  // g[200+tid]
      float sg = tanhf(g[400 + tid]);
      float so = 1.f / (1.f + __expf(-g[600 + tid]));
      c = sf * c + si * sg;
      float hn = so * tanhf(c);
      xout[t * EHDIM + tid] = hn;
      h[tid] = hn;
    }
    __syncthreads();
  }
}

// ---------------- eta chain (single block, W in LDS) ------------------------
#define WSTR 252
__global__ void k_eta(const float* __restrict__ Wmu, const float* __restrict__ bmu,
                      const float* __restrict__ Wls, const float* __restrict__ bls,
                      const float* __restrict__ lout, float* __restrict__ etas,
                      float* __restrict__ scal) {
  __shared__ __align__(16) float Wm[KDIM * WSTR + 4];
  __shared__ __align__(16) float Wl[KDIM * WSTR + 4];
  __shared__ __align__(16) float inp[256];
  __shared__ float mu_s[KDIM], ls_s[KDIM];
  int tid = threadIdx.x;  // 512
  for (int i = tid; i < KDIM * WSTR; i += 512) {
    int r = i / WSTR, c2 = i % WSTR;
    Wm[i] = (c2 < 250) ? Wmu[r * 250 + c2] : 0.f;
    Wl[i] = (c2 < 250) ? Wls[r * 250 + c2] : 0.f;
  }
  if (tid < 4) { Wm[KDIM * WSTR + tid] = 0.f; Wl[KDIM * WSTR + tid] = 0.f; }
  for (int i = tid; i < 256; i += 512) inp[i] = 0.f;
  __syncthreads();
  int wave = tid >> 6, lane = tid & 63;
  float kl = 0.f;
  for (int t = 0; t < TDIM; t++) {
    if (tid < EHDIM) inp[tid] = lout[t * EHDIM + tid];
    __syncthreads();
    float4 x4 = ((const float4*)inp)[lane];
    for (int jb = wave; jb < 2 * KDIM; jb += 8) {
      const float* Wrow = (jb < KDIM) ? (Wm + jb * WSTR) : (Wl + (jb - KDIM) * WSTR);
      float4 w4 = ((const float4*)Wrow)[lane];
      float acc = w4.x * x4.x + w4.y * x4.y + w4.z * x4.z + w4.w * x4.w;
      acc = wred64(acc);
      if (lane == 0) {
        if (jb < KDIM) mu_s[jb] = acc + bmu[jb];
        else ls_s[jb - KDIM] = acc + bls[jb - KDIM];
      }
    }
    __syncthreads();
    if (tid < 64) {
      float v = 0.f;
      if (tid < KDIM) {
        float m = mu_s[tid], ls = ls_s[tid];
        float ep = inp[EHDIM + tid];
        float d = m - ep;
        if (t == 0) v = 0.5f * ((__expf(ls) + d * d) / (1.f + EPSF) - 1.f - ls);
        else        v = 0.5f * ((__expf(ls) + d * d) / (DELTAF + EPSF) - 1.f + LOGD - ls);
        etas[t * KDIM + tid] = m;
      }
      v = wred64(v);
      if (tid == 0) kl += v;
    }
    __syncthreads();
    if (tid < KDIM) inp[EHDIM + tid] = mu_s[tid];
    __syncthreads();
  }
  if (tid == 0) scal[2] = kl;
}

// ---------------- h_pre = nb @ W_theta[:, :V]^T  (fp32 tiled, split-K) ------
#define HP_BK 32
#define HP_STRIDE 132
__global__ __launch_bounds__(256, 2) void k_hpre(const float* __restrict__ nb,
                                                 const float* __restrict__ Wth,
                                                 float* __restrict__ h_pre) {
  __shared__ __align__(16) float As[HP_BK * HP_STRIDE];
  __shared__ __align__(16) float Bs[HP_BK * HP_STRIDE];
  int tid = threadIdx.x;
  int nt = blockIdx.x, zc = blockIdx.y;
  int kt0 = zc * 20, ktend = min(938, kt0 + 20);
  float acc[8][8];
#pragma unroll
  for (int i = 0; i < 8; i++)
#pragma unroll
    for (int j = 0; j < 8; j++) acc[i][j] = 0.f;
  int tx = tid & 15, ty = tid >> 4;
  for (int kt = kt0; kt < ktend; kt++) {
    int v0 = kt * HP_BK;
#pragma unroll
    for (int r = 0; r < 4; r++) {
      int j = tid + r * 256;
      int row = j >> 3, c4 = (j & 7) * 4;
      int v = v0 + c4;
      float4 val = {0.f, 0.f, 0.f, 0.f};
      if (row < BDIM) {
        const float* base = nb + (size_t)row * VDIM + v;
        if (v + 3 < VDIM) val = *(const float4*)base;
        else {
          if (v < VDIM) val.x = base[0];
          if (v + 1 < VDIM) val.y = base[1];
          if (v + 2 < VDIM) val.z = base[2];
        }
      }
      As[(c4 + 0) * HP_STRIDE + row] = val.x;
      As[(c4 + 1) * HP_STRIDE + row] = val.y;
      As[(c4 + 2) * HP_STRIDE + row] = val.z;
      As[(c4 + 3) * HP_STRIDE + row] = val.w;
    }
#pragma unroll
    for (int r = 0; r < 4; r++) {
      int j = tid + r * 256;
      int row = j >> 3, c4 = (j & 7) * 4;
      int th = nt * 128 + row;
      int v = v0 + c4;
      float4 val = {0.f, 0.f, 0.f, 0.f};
      if (th < THDIM) {
        const float* base = Wth + (size_t)th * 30050 + v;
        if (v + 3 < VDIM) {
          float2 p0 = *(const float2*)base;
          float2 p1 = *(const float2*)(base + 2);
          val.x = p0.x; val.y = p0.y; val.z = p1.x; val.w = p1.y;
        } else {
          if (v < VDIM) val.x = base[0];
          if (v + 1 < VDIM) val.y = base[1];
          if (v + 2 < VDIM) val.z = base[2];
        }
      }
      Bs[(c4 + 0) * HP_STRIDE + row] = val.x;
      Bs[(c4 + 1) * HP_STRIDE + row] = val.y;
      Bs[(c4 + 2) * HP_STRIDE + row] = val.z;
      Bs[(c4 + 3) * HP_STRIDE + row] = val.w;
    }
    __syncthreads();
#pragma unroll
    for (int k = 0; k < HP_BK; k++) {
      float4 a0 = *(const float4*)&As[k * HP_STRIDE + ty * 8];
      float4 a1 = *(const float4*)&As[k * HP_STRIDE + ty * 8 + 4];
      float4 b0 = *(const float4*)&Bs[k * HP_STRIDE + tx * 8];
      float4 b1 = *(const float4*)&Bs[k * HP_STRIDE + tx * 8 + 4];
      float a[8] = {a0.x, a0.y, a0.z, a0.w, a1.x, a1.y, a1.z, a1.w};
      float b[8] = {b0.x, b0.y, b0.z, b0.w, b1.x, b1.y, b1.z, b1.w};
#pragma unroll
      for (int i = 0; i < 8; i++)
#pragma unroll
        for (int j = 0; j < 8; j++) acc[i][j] += a[i] * b[j];
    }
    __syncthreads();
  }
#pragma unroll
  for (int i = 0; i < 8; i++) {
    int bb = ty * 8 + i;
    if (bb >= BDIM) continue;
#pragma unroll
    for (int j = 0; j < 8; j++) {
      int th = nt * 128 + tx * 8 + j;
      if (th < THDIM) atomicAdd(&h_pre[bb * THDIM + th], acc[i][j]);
    }
  }
}

// ---------------- theta path: tanh, softmax, kl_theta -----------------------
__global__ void k_theta(const float* __restrict__ hpre, const float* __restrict__ bth,
                        const float* __restrict__ Wth, const float* __restrict__ Wmt,
                        const float* __restrict__ bmt, const float* __restrict__ Wlt,
                        const float* __restrict__ blt, const float* __restrict__ etas,
                        const int* __restrict__ times, float* __restrict__ theta,
                        float* __restrict__ scal) {
  __shared__ float et[KDIM];
  __shared__ float hl[THDIM];
  __shared__ float mu_s[KDIM], ls_s[KDIM];
  int b = blockIdx.x, tid = threadIdx.x;
  if (tid < KDIM) et[tid] = etas[times[b] * KDIM + tid];
  __syncthreads();
  for (int th = tid; th < THDIM; th += 256) {
    float acc = hpre[b * THDIM + th] + bth[th];
    const float* wrow = Wth + (size_t)th * 30050 + VDIM;
#pragma unroll 10
    for (int k = 0; k < KDIM; k++) acc += et[k] * wrow[k];
    hl[th] = tanhf(acc);
  }
  __syncthreads();
  int wave = tid >> 6, lane = tid & 63;
  for (int jb = wave; jb < 2 * KDIM; jb += 4) {
    const float* row = (jb < KDIM) ? (Wmt + jb * THDIM) : (Wlt + (jb - KDIM) * THDIM);
    float acc = 0.f;
#pragma unroll
    for (int m = 0; m < 13; m++) { int j = m * 64 + lane; if (j < THDIM) acc += row[j] * hl[j]; }
    acc = wred64(acc);
    if (lane == 0) {
      if (jb < KDIM) mu_s[jb] = acc + bmt[jb];
      else ls_s[jb - KDIM] = acc + blt[jb - KDIM];
    }
  }
  __syncthreads();
  if (tid < 64) {
    float m = (tid < KDIM) ? mu_s[tid] : -1e30f;
    float mx = m;
#pragma unroll
    for (int o = 32; o >= 1; o >>= 1) mx = fmaxf(mx, __shfl_xor(mx, o, 64));
    float e = (tid < KDIM) ? __expf(m - mx) : 0.f;
    float s = wred64(e);
    if (tid < KDIM) theta[b * KDIM + tid] = e / s;
    float v = 0.f;
    if (tid < KDIM) {
      float ls = ls_s[tid];
      float d = mu_s[tid] - et[tid];
      v = 0.5f * ((__expf(ls) + d * d) / (1.f + EPSF) - 1.f - ls);
    }
    v = wred64(v);
    if (tid == 0) atomicAdd(&scal[3], v);
  }
}

// ---------------- kl_alpha ---------------------------------------------------
__global__ void k_klalpha(const float* __restrict__ mu, const float* __restrict__ ls,
                          float* __restrict__ scal) {
  int idx = blockIdx.x * 256 + threadIdx.x;
  float v = 0.f;
  if (idx < KDIM * TDIM * EDIM) {
    int t = (idx / EDIM) % TDIM;
    float l = ls[idx], m = mu[idx];
    if (t == 0) v = 0.5f * ((__expf(l) + m * m) / (1.f + EPSF) - 1.f - l);
    else { float d = m - mu[idx - EDIM]; v = 0.5f * ((__expf(l) + d * d) / (DELTAF + EPSF) - 1.f + LOGD - l); }
  }
  v = wred64(v);
  __shared__ float p[4];
  if ((threadIdx.x & 63) == 0) p[threadIdx.x >> 6] = v;
  __syncthreads();
  if (threadIdx.x == 0) atomicAdd(&scal[1], p[0] + p[1] + p[2] + p[3]);
}

// ---------------- time buckets ----------------------------------------------
__global__ void k_bucket(const int* __restrict__ times, int* __restrict__ bcnt,
                         int* __restrict__ bucket) {
  __shared__ int cnt[TDIM];
  int tid = threadIdx.x;  // 128
  if (tid < TDIM) cnt[tid] = 0;
  __syncthreads();
  if (tid < BDIM) {
    int t = times[tid];
    int s = atomicAdd(&cnt[t], 1);
    bucket[t * 128 + s] = tid;
  }
  __syncthreads();
  if (tid < TDIM) bcnt[tid] = cnt[tid];
}

// ---------------- wgt[b][k] = theta[b][k] / Z[t_b*64+k] ---------------------
__global__ void k_wgt(const float* __restrict__ theta, const float* __restrict__ Z,
                      const int* __restrict__ times, float* __restrict__ wgt) {
  int idx = blockIdx.x * 256 + threadIdx.x;  // 6400
  if (idx >= BDIM * 64) return;
  int b = idx >> 6, k = idx & 63;
  float v = 0.f;
  if (k < KDIM) v = theta[b * KDIM + k] / Z[times[b] * 64 + k];
  wgt[idx] = v;
}

// ---------------- shared MFMA helpers ---------------------------------------
__device__ inline void stage_B(const float* __restrict__ we, int vbase,
                               unsigned short* LB, int tid) {
  for (int q = tid; q < VT * 75; q += 256) {
    int vp = q / 75, e4 = (q % 75) * 4;
    float4 w = *(const float4*)(we + (size_t)(vbase + vp) * EDIM + e4);
    unsigned* p32 = (unsigned*)(LB + vp * LBSTR + e4);
    p32[0] = (unsigned)f2bf(w.x) | ((unsigned)f2bf(w.y) << 16);
    p32[1] = (unsigned)f2bf(w.z) | ((unsigned)f2bf(w.w) << 16);
  }
  for (int q = tid; q < VT * 28; q += 256) {
    int vp = q / 28, e = 300 + q % 28;
    LB[vp * LBSTR + e] = 0;
  }
}

__device__ inline void quad_mainloop(const unsigned short* __restrict__ A2,
                                     const unsigned short* LB, int quad, int lane,
                                     f32x4 (&acc)[4][5]) {
  int mrow = quad * 64 + (lane & 15);
  int eoff = (lane >> 4) * 8;
  const bf16x8* ap[4];
#pragma unroll
  for (int ss = 0; ss < 4; ss++)
    ap[ss] = (const bf16x8*)(A2 + (size_t)(mrow + ss * 16) * KPAD + eoff);
  const unsigned short* bp = LB + (lane & 15) * LBSTR + eoff;
#pragma unroll
  for (int kk = 0; kk < 10; kk++) {
    bf16x8 a[4];
#pragma unroll
    for (int ss = 0; ss < 4; ss++) a[ss] = ap[ss][kk * 4];
#pragma unroll
    for (int cf = 0; cf < 5; cf++) {
      bf16x8 b = *(const bf16x8*)(bp + cf * 16 * LBSTR + kk * 32);
#pragma unroll
      for (int ss = 0; ss < 4; ss++)
        acc[ss][cf] = __builtin_amdgcn_mfma_f32_16x16x32_bf16(a[ss], b, acc[ss][cf], 0, 0, 0);
    }
  }
}

// ---------------- pass A: Z[t*64+k] = sum_v exp(logits) ---------------------
__global__ __launch_bounds__(256, 2) void k_passA(const float* __restrict__ we,
                                                  const unsigned short* __restrict__ A2,
                                                  float* __restrict__ Z) {
  __shared__ __align__(16) unsigned short LB[VT * LBSTR];
  int tid = threadIdx.x, vbase = blockIdx.x * VT;
  stage_B(we, vbase, LB, tid);
  __syncthreads();
  int wave = tid >> 6, lane = tid & 63;
  for (int q = wave; q < TDIM; q += 4) {
    f32x4 acc[4][5];
#pragma unroll
    for (int ss = 0; ss < 4; ss++)
#pragma unroll
      for (int cf = 0; cf < 5; cf++) acc[ss][cf] = (f32x4){0.f, 0.f, 0.f, 0.f};
    quad_mainloop(A2, LB, q, lane, acc);
#pragma unroll
    for (int ss = 0; ss < 4; ss++) {
#pragma unroll
      for (int r = 0; r < 4; r++) {
        float s = __expf(acc[ss][0][r]) + __expf(acc[ss][1][r]) + __expf(acc[ss][2][r]) +
                  __expf(acc[ss][3][r]) + __expf(acc[ss][4][r]);
        s += __shfl_xor(s, 1, 64); s += __shfl_xor(s, 2, 64);
        s += __shfl_xor(s, 4, 64); s += __shfl_xor(s, 8, 64);
        if ((lane & 15) == 0)
          atomicAdd(&Z[q * 64 + ss * 16 + (lane >> 4) * 4 + r], s);
      }
    }
  }
}

// ---------------- pass B: nll epilogue --------------------------------------
__global__ __launch_bounds__(256, 2) void k_passB(const float* __restrict__ we,
                                                  const unsigned short* __restrict__ A2,
                                                  const float* __restrict__ wgt,
                                                  const float* __restrict__ bows,
                                                  const int* __restrict__ bcnt,
                                                  const int* __restrict__ bucket,
                                                  float* __restrict__ scal) {
  __shared__ __align__(16) unsigned short LB[VT * LBSTR];
  int tid = threadIdx.x, vbase = blockIdx.x * VT;
  stage_B(we, vbase, LB, tid);
  __syncthreads();
  int wave = tid >> 6, lane = tid & 63;
  float nacc = 0.f;
  for (int t = wave; t < TDIM; t += 4) {
    f32x4 acc[4][5];
#pragma unroll
    for (int ss = 0; ss < 4; ss++)
#pragma unroll
      for (int cf = 0; cf < 5; cf++) acc[ss][cf] = (f32x4){0.f, 0.f, 0.f, 0.f};
    quad_mainloop(A2, LB, t, lane, acc);
#pragma unroll
    for (int ss = 0; ss < 4; ss++)
#pragma unroll
      for (int cf = 0; cf < 5; cf++)
#pragma unroll
        for (int r = 0; r < 4; r++) acc[ss][cf][r] = __expf(acc[ss][cf][r]);
    int cnt = bcnt[t];
    for (int n = 0; n < cnt; n++) {
      int b = bucket[t * 128 + n];
      float4 w[4];
#pragma unroll
      for (int ss = 0; ss < 4; ss++)
        w[ss] = *(const float4*)(wgt + b * 64 + ss * 16 + (lane >> 4) * 4);
#pragma unroll
      for (int cf = 0; cf < 5; cf++) {
        float local = 0.f;
#pragma unroll
        for (int ss = 0; ss < 4; ss++)
          local += w[ss].x * acc[ss][cf][0] + w[ss].y * acc[ss][cf][1] +
                   w[ss].z * acc[ss][cf][2] + w[ss].w * acc[ss][cf][3];
        local += __shfl_xor(local, 16, 64);
        local += __shfl_xor(local, 32, 64);
        int v = vbase + cf * 16 + (lane & 15);
        float contrib = bows[(size_t)b * VDIM + v] * __logf(local + EPSF);
        if (lane < 16) nacc += contrib;
      }
    }
  }
  nacc = wred64(nacc);
  __shared__ float p[4];
  if (lane == 0) p[wave] = nacc;
  __syncthreads();
  if (tid == 0) atomicAdd(&scal[0], p[0] + p[1] + p[2] + p[3]);
}

// ---------------- finalize ---------------------------------------------------
__global__ void k_finalize(const float* __restrict__ scal, float* __restrict__ out) {
  if (threadIdx.x == 0 && blockIdx.x == 0) {
    float nll = -scal[0];
    out[0] = nll + scal[1] + scal[2] + scal[3];
    out[1] = nll;
    out[2] = scal[1];
    out[3] = scal[2];
    out[4] = scal[3];
  }
}

extern "C" void kernel_launch(void* const* d_in, const int* in_sizes, int n_in,
                              void* d_out, int out_size, void* d_ws, size_t ws_size,
                              hipStream_t stream) {
  const float* bows  = (const float*)d_in[0];
  const float* nbows = (const float*)d_in[1];
  const float* rnn   = (const float*)d_in[2];
  const float* wemb  = (const float*)d_in[3];
  const float* mua   = (const float*)d_in[4];
  const float* lsa   = (const float*)d_in[5];
  const float* Wth   = (const float*)d_in[6];
  const float* bth   = (const float*)d_in[7];
  const float* Wmt   = (const float*)d_in[8];
  const float* bmt   = (const float*)d_in[9];
  const float* Wlt   = (const float*)d_in[10];
  const float* blt   = (const float*)d_in[11];
  const float* Wmap  = (const float*)d_in[12];
  const float* bmap  = (const float*)d_in[13];
  const float* Wih   = (const float*)d_in[14];
  const float* Whh   = (const float*)d_in[15];
  const float* bihp  = (const float*)d_in[16];
  const float* bhhp  = (const float*)d_in[17];
  const float* Wme   = (const float*)d_in[18];
  const float* bme   = (const float*)d_in[19];
  const float* Wle   = (const float*)d_in[20];
  const float* ble   = (const float*)d_in[21];
  const int* times   = (const int*)d_in[22];

  float* ws = (float*)d_ws;
  float* scal  = ws;                 // 8
  float* Z     = ws + 8;             // 2560
  float* hpre  = ws + 2568;          // 80000
  float* omap  = ws + 82568;         // 8000   (end of zeroed region: 90568 floats)
  float* xa    = ws + 90568;         // 8000
  float* xb    = ws + 98568;         // 8000
  float* lout  = ws + 106568;        // 8000
  float* Gin   = ws + 114568;        // 32000
  unsigned* WhhT = (unsigned*)(ws + 146568);   // 240000
  float* etas  = ws + 386568;        // 2000
  float* theta = ws + 388568;        // 5000
  float* wgt   = ws + 393568;        // 6400
  int* bcnt    = (int*)(ws + 399968);          // 64
  int* bucket  = (int*)(ws + 400032);          // 5120
  unsigned short* A2 = (unsigned short*)(ws + 405152);  // 819200 ushorts

  hipMemsetAsync(ws, 0, 90568 * sizeof(float), stream);

  k_prep_A2<<<3200, 256, 0, stream>>>(mua, A2);
  k_map<<<dim3(100, 4), 256, 0, stream>>>(rnn, Wmap, bmap, omap);
  k_wt<<<300, 256, 0, stream>>>(Whh, WhhT);
  k_bucket<<<1, 128, 0, stream>>>(times, bcnt, bucket);
  k_passA<<<NBLK_V, 256, 0, stream>>>(wemb, A2, Z);

  k_igemm<<<400, 256, 0, stream>>>(Wih, bihp, bhhp, omap, Gin, 0);
  k_rec<<<1, 1024, 0, stream>>>(WhhT, Gin, xa);
  k_igemm<<<400, 256, 0, stream>>>(Wih, bihp, bhhp, xa, Gin, 1);
  k_rec<<<1, 1024, 0, stream>>>(WhhT + 100 * 800, Gin, xb);
  k_igemm<<<400, 256, 0, stream>>>(Wih, bihp, bhhp, xb, Gin, 2);
  k_rec<<<1, 1024, 0, stream>>>(WhhT + 200 * 800, Gin, lout);

  k_eta<<<1, 512, 0, stream>>>(Wme, bme, Wle, ble, lout, etas, scal);
  k_hpre<<<dim3(7, 47), 256, 0, stream>>>(nbows, Wth, hpre);
  k_theta<<<100, 256, 0, stream>>>(hpre, bth, Wth, Wmt, bmt, Wlt, blt, etas, times, theta, scal);
  k_wgt<<<25, 256, 0, stream>>>(theta, Z, times, wgt);
  k_klalpha<<<2344, 256, 0, stream>>>(mua, lsa, scal);
  k_passB<<<NBLK_V, 256, 0, stream>>>(wemb, A2, wgt, bows, bcnt, bucket, scal);
  k_finalize<<<1, 64, 0, stream>>>(scal, (float*)d_out);
}

// Round 2
// 2079.896 us; speedup vs baseline: 1.1009x; 1.1009x over previous
//
#include <hip/hip_runtime.h>

#define KDIM 50
#define TDIM 40
#define VDIM 30000
#define THDIM 800
#define EHDIM 200
#define EDIM 300
#define BDIM 100
#define DELTAF 0.005f
#define EPSF 1e-6f
#define LOGD (-5.2983174f)
#define MROWS 2560   // TDIM*64 rows for MFMA A operand
#define KPAD 320     // E padded to 320
#define VROWS 30080  // V padded to 235*128
#define VT 80        // v-tile per MFMA block (fallback path)
#define NBLK_V 375   // 30000/80 (fallback path)
#define LBSTR 328    // fallback LDS B-tile row stride

typedef __attribute__((ext_vector_type(8))) short bf16x8;
typedef __attribute__((ext_vector_type(4))) float f32x4;
typedef unsigned int u32;

__device__ inline float wred64(float v) {
  v += __shfl_xor(v, 32, 64); v += __shfl_xor(v, 16, 64);
  v += __shfl_xor(v, 8, 64);  v += __shfl_xor(v, 4, 64);
  v += __shfl_xor(v, 2, 64);  v += __shfl_xor(v, 1, 64);
  return v;
}

__device__ inline unsigned short f2bf(float f) {
  union { float f; unsigned u; } x; x.f = f;
  unsigned r = x.u + 0x7fffu + ((x.u >> 16) & 1u);
  return (unsigned short)(r >> 16);
}

__device__ inline void gload_lds16(const void* g, void* l) {
  __builtin_amdgcn_global_load_lds(
      (const __attribute__((address_space(1))) u32*)g,
      (__attribute__((address_space(3))) u32*)l, 16, 0, 0);
}

// ---------------- A2 prep: mu_q_alpha[k][t][e] -> bf16 A2[t*64+k][e<320] ----
__global__ void k_prep_A2(const float* __restrict__ mu_q, unsigned short* __restrict__ A2) {
  int idx = blockIdx.x * 256 + threadIdx.x;   // 2560*320 = 819200
  if (idx >= MROWS * KPAD) return;
  int m = idx / KPAD, e = idx % KPAD;
  int t = m >> 6, kp = m & 63;
  float v = 0.f;
  if (kp < KDIM && e < EDIM) v = mu_q[(kp * TDIM + t) * EDIM + e];
  A2[idx] = f2bf(v);
}

// ---------------- B2 prep: word_emb fp32 [30000][300] -> bf16 [30080][320] --
__global__ void k_prep_B(const float* __restrict__ we, unsigned short* __restrict__ B2) {
  int idx = blockIdx.x * 256 + threadIdx.x;   // 30080*80 = 2406400
  if (idx >= VROWS * 80) return;
  int v = idx / 80, e4 = (idx % 80) * 4;
  ushort4 o = {0, 0, 0, 0};
  if (v < VDIM && e4 < EDIM) {
    float4 w = *(const float4*)(we + (size_t)v * EDIM + e4);
    o.x = f2bf(w.x); o.y = f2bf(w.y); o.z = f2bf(w.z); o.w = f2bf(w.w);
  }
  *(ushort4*)(B2 + (size_t)v * KPAD + e4) = o;
}

// ---------------- out_map = rnn_inp @ W_map^T + b_map  [40,200] -------------
// LDS-staged, transposed tiles: rs[vv][t], wsb[vv][e]; 16 FMA per 2 ds_read_b128
#define MP_VS 96
#define RS_STR 44
#define WS_STR 104
__global__ __launch_bounds__(256) void k_map2(const float* __restrict__ rnn,
                                              const float* __restrict__ Wmap,
                                              const float* __restrict__ bmap,
                                              float* __restrict__ omap) {
  __shared__ __align__(16) float rs[MP_VS * RS_STR];
  __shared__ __align__(16) float wsb[MP_VS * WS_STR];
  int c = blockIdx.x, eh = blockIdx.y;
  int v0 = c * MP_VS, e0 = eh * 100;
  int tid = threadIdx.x;
  for (int idx = tid; idx < TDIM * MP_VS; idx += 256) {
    int t = idx / MP_VS, vv = idx % MP_VS;
    int v = v0 + vv;
    rs[vv * RS_STR + t] = (v < VDIM) ? rnn[(size_t)t * VDIM + v] : 0.f;
  }
  for (int idx = tid; idx < 100 * MP_VS; idx += 256) {
    int e = idx / MP_VS, vv = idx % MP_VS;
    int v = v0 + vv;
    wsb[vv * WS_STR + e] = (v < VDIM) ? Wmap[(size_t)(e0 + e) * VDIM + v] : 0.f;
  }
  __syncthreads();
  if (tid >= 250) return;
  int eg = tid / 10, tg = tid % 10;
  float acc[4][4];
#pragma unroll
  for (int i = 0; i < 4; i++)
#pragma unroll
    for (int j = 0; j < 4; j++) acc[i][j] = 0.f;
  int nvv = min(MP_VS, VDIM - v0);
  for (int vv = 0; vv < nvv; vv++) {
    float4 wv = *(const float4*)&wsb[vv * WS_STR + eg * 4];
    float4 rv = *(const float4*)&rs[vv * RS_STR + tg * 4];
    float wa[4] = {wv.x, wv.y, wv.z, wv.w};
    float ra[4] = {rv.x, rv.y, rv.z, rv.w};
#pragma unroll
    for (int i = 0; i < 4; i++)
#pragma unroll
      for (int j = 0; j < 4; j++) acc[i][j] += wa[i] * ra[j];
  }
#pragma unroll
  for (int i = 0; i < 4; i++) {
    int e = e0 + eg * 4 + i;
#pragma unroll
    for (int j = 0; j < 4; j++) {
      int t = tg * 4 + j;
      float a = acc[i][j];
      if (c == 0) a += bmap[e];
      atomicAdd(&omap[t * EHDIM + e], a);
    }
  }
}

// ---------------- Whh transpose+pack to bf16 pairs: WhhT[l][jp][i] ----------
__global__ void k_wt(const float* __restrict__ Whh, unsigned* __restrict__ WhhT) {
  int l = blockIdx.x / 100, jp = blockIdx.x % 100;
  for (int i = threadIdx.x; i < THDIM; i += 256) {
    float w0 = Whh[(l * THDIM + i) * EHDIM + 2 * jp];
    float w1 = Whh[(l * THDIM + i) * EHDIM + 2 * jp + 1];
    WhhT[(l * 100 + jp) * THDIM + i] = (unsigned)f2bf(w0) | ((unsigned)f2bf(w1) << 16);
  }
}

// ---------------- LSTM input GEMM: G[t][i] = Wih[l][i]·x[t] + bih + bhh -----
__global__ void k_igemm(const float* __restrict__ Wih, const float* __restrict__ bih,
                        const float* __restrict__ bhh, const float* __restrict__ x,
                        float* __restrict__ G, int l) {
  int wave = threadIdx.x >> 6, lane = threadIdx.x & 63;
  int d0 = blockIdx.x * 80 + wave * 20;
  for (int n = 0; n < 20; n++) {
    int d = d0 + n;
    int t = d / THDIM, i = d % THDIM;
    const float* row = Wih + (l * THDIM + i) * EHDIM;
    const float* xt = x + t * EHDIM;
    float acc = 0.f;
#pragma unroll
    for (int m = 0; m < 4; m++) { int j = m * 64 + lane; if (j < EHDIM) acc += row[j] * xt[j]; }
    acc = wred64(acc);
    if (lane == 0) G[t * THDIM + i] = acc + bih[l * THDIM + i] + bhh[l * THDIM + i];
  }
}

// ---------------- LSTM recurrence (single block, streams bf16 WhhT) ---------
__global__ __launch_bounds__(1024) void k_rec(const unsigned* __restrict__ WT,
                                              const float* __restrict__ G,
                                              float* __restrict__ xout) {
  __shared__ __align__(16) float h[EHDIM];
  __shared__ float g[THDIM];
  int tid = threadIdx.x;
  if (tid < EHDIM) h[tid] = 0.f;
  float c = 0.f;
  __syncthreads();
  for (int t = 0; t < TDIM; t++) {
    if (tid < THDIM) {
      float acc = G[t * THDIM + tid];
      const unsigned* wp = WT + tid;
      const float4* h4 = (const float4*)h;
      for (int q = 0; q < 50; q++) {
        float4 hq = h4[q];
        unsigned wa = wp[(2 * q) * THDIM];
        unsigned wb = wp[(2 * q + 1) * THDIM];
        union { unsigned u; float f; } la, ha, lb, hb;
        la.u = wa << 16; ha.u = wa & 0xffff0000u;
        lb.u = wb << 16; hb.u = wb & 0xffff0000u;
        acc += la.f * hq.x + ha.f * hq.y + lb.f * hq.z + hb.f * hq.w;
      }
      g[tid] = acc;
    }
    __syncthreads();
    if (tid < EHDIM) {
      float si = 1.f / (1.f + __expf(-g[tid]));
      float sf = 1.f / (1.f + __expf(-g[200 + tid]));
      float sg = tanhf(g[400 + tid]);
      float so = 1.f / (1.f + __expf(-g[600 + tid]));
      c = sf * c + si * sg;
      float hn = so * tanhf(c);
      xout[t * EHDIM + tid] = hn;
      h[tid] = hn;
    }
    __syncthreads();
  }
}

// ---------------- eta chain (single block, W in LDS) ------------------------
#define WSTR 252
__global__ void k_eta(const float* __restrict__ Wmu, const float* __restrict__ bmu,
                      const float* __restrict__ Wls, const float* __restrict__ bls,
                      const float* __restrict__ lout, float* __restrict__ etas,
                      float* __restrict__ scal) {
  __shared__ __align__(16) float Wm[KDIM * WSTR + 4];
  __shared__ __align__(16) float Wl[KDIM * WSTR + 4];
  __shared__ __align__(16) float inp[256];
  __shared__ float mu_s[KDIM], ls_s[KDIM];
  int tid = threadIdx.x;  // 512
  for (int i = tid; i < KDIM * WSTR; i += 512) {
    int r = i / WSTR, c2 = i % WSTR;
    Wm[i] = (c2 < 250) ? Wmu[r * 250 + c2] : 0.f;
    Wl[i] = (c2 < 250) ? Wls[r * 250 + c2] : 0.f;
  }
  if (tid < 4) { Wm[KDIM * WSTR + tid] = 0.f; Wl[KDIM * WSTR + tid] = 0.f; }
  for (int i = tid; i < 256; i += 512) inp[i] = 0.f;
  __syncthreads();
  int wave = tid >> 6, lane = tid & 63;
  float kl = 0.f;
  for (int t = 0; t < TDIM; t++) {
    if (tid < EHDIM) inp[tid] = lout[t * EHDIM + tid];
    __syncthreads();
    float4 x4 = ((const float4*)inp)[lane];
    for (int jb = wave; jb < 2 * KDIM; jb += 8) {
      const float* Wrow = (jb < KDIM) ? (Wm + jb * WSTR) : (Wl + (jb - KDIM) * WSTR);
      float4 w4 = ((const float4*)Wrow)[lane];
      float acc = w4.x * x4.x + w4.y * x4.y + w4.z * x4.z + w4.w * x4.w;
      acc = wred64(acc);
      if (lane == 0) {
        if (jb < KDIM) mu_s[jb] = acc + bmu[jb];
        else ls_s[jb - KDIM] = acc + bls[jb - KDIM];
      }
    }
    __syncthreads();
    if (tid < 64) {
      float v = 0.f;
      if (tid < KDIM) {
        float m = mu_s[tid], ls = ls_s[tid];
        float ep = inp[EHDIM + tid];
        float d = m - ep;
        if (t == 0) v = 0.5f * ((__expf(ls) + d * d) / (1.f + EPSF) - 1.f - ls);
        else        v = 0.5f * ((__expf(ls) + d * d) / (DELTAF + EPSF) - 1.f + LOGD - ls);
        etas[t * KDIM + tid] = m;
      }
      v = wred64(v);
      if (tid == 0) kl += v;
    }
    __syncthreads();
    if (tid < KDIM) inp[EHDIM + tid] = mu_s[tid];
    __syncthreads();
  }
  if (tid == 0) scal[2] = kl;
}

// ---------------- h_pre = nb @ W_theta[:, :V]^T  (fp32 tiled, split-K) ------
#define HP_BK 32
#define HP_STRIDE 132
__global__ __launch_bounds__(256, 2) void k_hpre(const float* __restrict__ nb,
                                                 const float* __restrict__ Wth,
                                                 float* __restrict__ h_pre) {
  __shared__ __align__(16) float As[HP_BK * HP_STRIDE];
  __shared__ __align__(16) float Bs[HP_BK * HP_STRIDE];
  int tid = threadIdx.x;
  int nt = blockIdx.x, zc = blockIdx.y;
  int kt0 = zc * 20, ktend = min(938, kt0 + 20);
  float acc[8][8];
#pragma unroll
  for (int i = 0; i < 8; i++)
#pragma unroll
    for (int j = 0; j < 8; j++) acc[i][j] = 0.f;
  int tx = tid & 15, ty = tid >> 4;
  for (int kt = kt0; kt < ktend; kt++) {
    int v0 = kt * HP_BK;
#pragma unroll
    for (int r = 0; r < 4; r++) {
      int j = tid + r * 256;
      int row = j >> 3, c4 = (j & 7) * 4;
      int v = v0 + c4;
      float4 val = {0.f, 0.f, 0.f, 0.f};
      if (row < BDIM) {
        const float* base = nb + (size_t)row * VDIM + v;
        if (v + 3 < VDIM) val = *(const float4*)base;
        else {
          if (v < VDIM) val.x = base[0];
          if (v + 1 < VDIM) val.y = base[1];
          if (v + 2 < VDIM) val.z = base[2];
        }
      }
      As[(c4 + 0) * HP_STRIDE + row] = val.x;
      As[(c4 + 1) * HP_STRIDE + row] = val.y;
      As[(c4 + 2) * HP_STRIDE + row] = val.z;
      As[(c4 + 3) * HP_STRIDE + row] = val.w;
    }
#pragma unroll
    for (int r = 0; r < 4; r++) {
      int j = tid + r * 256;
      int row = j >> 3, c4 = (j & 7) * 4;
      int th = nt * 128 + row;
      int v = v0 + c4;
      float4 val = {0.f, 0.f, 0.f, 0.f};
      if (th < THDIM) {
        const float* base = Wth + (size_t)th * 30050 + v;
        if (v + 3 < VDIM) {
          float2 p0 = *(const float2*)base;
          float2 p1 = *(const float2*)(base + 2);
          val.x = p0.x; val.y = p0.y; val.z = p1.x; val.w = p1.y;
        } else {
          if (v < VDIM) val.x = base[0];
          if (v + 1 < VDIM) val.y = base[1];
          if (v + 2 < VDIM) val.z = base[2];
        }
      }
      Bs[(c4 + 0) * HP_STRIDE + row] = val.x;
      Bs[(c4 + 1) * HP_STRIDE + row] = val.y;
      Bs[(c4 + 2) * HP_STRIDE + row] = val.z;
      Bs[(c4 + 3) * HP_STRIDE + row] = val.w;
    }
    __syncthreads();
#pragma unroll
    for (int k = 0; k < HP_BK; k++) {
      float4 a0 = *(const float4*)&As[k * HP_STRIDE + ty * 8];
      float4 a1 = *(const float4*)&As[k * HP_STRIDE + ty * 8 + 4];
      float4 b0 = *(const float4*)&Bs[k * HP_STRIDE + tx * 8];
      float4 b1 = *(const float4*)&Bs[k * HP_STRIDE + tx * 8 + 4];
      float a[8] = {a0.x, a0.y, a0.z, a0.w, a1.x, a1.y, a1.z, a1.w};
      float b[8] = {b0.x, b0.y, b0.z, b0.w, b1.x, b1.y, b1.z, b1.w};
#pragma unroll
      for (int i = 0; i < 8; i++)
#pragma unroll
        for (int j = 0; j < 8; j++) acc[i][j] += a[i] * b[j];
    }
    __syncthreads();
  }
#pragma unroll
  for (int i = 0; i < 8; i++) {
    int bb = ty * 8 + i;
    if (bb >= BDIM) continue;
#pragma unroll
    for (int j = 0; j < 8; j++) {
      int th = nt * 128 + tx * 8 + j;
      if (th < THDIM) atomicAdd(&h_pre[bb * THDIM + th], acc[i][j]);
    }
  }
}

// ---------------- theta path: tanh, softmax, kl_theta -----------------------
__global__ void k_theta(const float* __restrict__ hpre, const float* __restrict__ bth,
                        const float* __restrict__ Wth, const float* __restrict__ Wmt,
                        const float* __restrict__ bmt, const float* __restrict__ Wlt,
                        const float* __restrict__ blt, const float* __restrict__ etas,
                        const int* __restrict__ times, float* __restrict__ theta,
                        float* __restrict__ scal) {
  __shared__ float et[KDIM];
  __shared__ float hl[THDIM];
  __shared__ float mu_s[KDIM], ls_s[KDIM];
  int b = blockIdx.x, tid = threadIdx.x;
  if (tid < KDIM) et[tid] = etas[times[b] * KDIM + tid];
  __syncthreads();
  for (int th = tid; th < THDIM; th += 256) {
    float acc = hpre[b * THDIM + th] + bth[th];
    const float* wrow = Wth + (size_t)th * 30050 + VDIM;
#pragma unroll 10
    for (int k = 0; k < KDIM; k++) acc += et[k] * wrow[k];
    hl[th] = tanhf(acc);
  }
  __syncthreads();
  int wave = tid >> 6, lane = tid & 63;
  for (int jb = wave; jb < 2 * KDIM; jb += 4) {
    const float* row = (jb < KDIM) ? (Wmt + jb * THDIM) : (Wlt + (jb - KDIM) * THDIM);
    float acc = 0.f;
#pragma unroll
    for (int m = 0; m < 13; m++) { int j = m * 64 + lane; if (j < THDIM) acc += row[j] * hl[j]; }
    acc = wred64(acc);
    if (lane == 0) {
      if (jb < KDIM) mu_s[jb] = acc + bmt[jb];
      else ls_s[jb - KDIM] = acc + blt[jb - KDIM];
    }
  }
  __syncthreads();
  if (tid < 64) {
    float m = (tid < KDIM) ? mu_s[tid] : -1e30f;
    float mx = m;
#pragma unroll
    for (int o = 32; o >= 1; o >>= 1) mx = fmaxf(mx, __shfl_xor(mx, o, 64));
    float e = (tid < KDIM) ? __expf(m - mx) : 0.f;
    float s = wred64(e);
    if (tid < KDIM) theta[b * KDIM + tid] = e / s;
    float v = 0.f;
    if (tid < KDIM) {
      float ls = ls_s[tid];
      float d = mu_s[tid] - et[tid];
      v = 0.5f * ((__expf(ls) + d * d) / (1.f + EPSF) - 1.f - ls);
    }
    v = wred64(v);
    if (tid == 0) atomicAdd(&scal[3], v);
  }
}

// ---------------- kl_alpha ---------------------------------------------------
__global__ void k_klalpha(const float* __restrict__ mu, const float* __restrict__ ls,
                          float* __restrict__ scal) {
  int idx = blockIdx.x * 256 + threadIdx.x;
  float v = 0.f;
  if (idx < KDIM * TDIM * EDIM) {
    int t = (idx / EDIM) % TDIM;
    float l = ls[idx], m = mu[idx];
    if (t == 0) v = 0.5f * ((__expf(l) + m * m) / (1.f + EPSF) - 1.f - l);
    else { float d = m - mu[idx - EDIM]; v = 0.5f * ((__expf(l) + d * d) / (DELTAF + EPSF) - 1.f + LOGD - l); }
  }
  v = wred64(v);
  __shared__ float p[4];
  if ((threadIdx.x & 63) == 0) p[threadIdx.x >> 6] = v;
  __syncthreads();
  if (threadIdx.x == 0) atomicAdd(&scal[1], p[0] + p[1] + p[2] + p[3]);
}

// ---------------- time buckets ----------------------------------------------
__global__ void k_bucket(const int* __restrict__ times, int* __restrict__ bcnt,
                         int* __restrict__ bucket) {
  __shared__ int cnt[TDIM];
  int tid = threadIdx.x;  // 128
  if (tid < TDIM) cnt[tid] = 0;
  __syncthreads();
  if (tid < BDIM) {
    int t = times[tid];
    int s = atomicAdd(&cnt[t], 1);
    bucket[t * 128 + s] = tid;
  }
  __syncthreads();
  if (tid < TDIM) bcnt[tid] = cnt[tid];
}

// ---------------- wgt[b][k] = theta[b][k] / Z[t_b*64+k] ---------------------
__global__ void k_wgt(const float* __restrict__ theta, const float* __restrict__ Z,
                      const int* __restrict__ times, float* __restrict__ wgt) {
  int idx = blockIdx.x * 256 + threadIdx.x;  // 6400
  if (idx >= BDIM * 64) return;
  int b = idx >> 6, k = idx & 63;
  float v = 0.f;
  if (k < KDIM) v = theta[b * KDIM + k] / Z[times[b] * 64 + k];
  wgt[idx] = v;
}

// ================= NEW: m97-style MFMA GEMM for both passes =================
// 128x128 tile, BK=32, global_load_lds(16B) staging for A and B,
// XOR slot-swizzle so ds_read_b128 frag reads are ~2-way bank aliased.
template <bool PASSB>
__global__ __launch_bounds__(256) void k_gemm(
    const unsigned short* __restrict__ A2, const unsigned short* __restrict__ B2,
    float* __restrict__ Z, const float* __restrict__ wgt,
    const float* __restrict__ bows, const int* __restrict__ bcnt,
    const int* __restrict__ bucket, float* __restrict__ scal) {
  __shared__ __align__(16) unsigned short As[128 * 32];
  __shared__ __align__(16) unsigned short Bs[128 * 32];
  __shared__ float p[4];
  int tid = threadIdx.x, wv = tid >> 6, lane = tid & 63;
  int m0 = blockIdx.y * 128;
  int vbase = blockIdx.x * 128;
  f32x4 acc[4][4];
#pragma unroll
  for (int i = 0; i < 4; i++)
#pragma unroll
    for (int j = 0; j < 4; j++) acc[i][j] = (f32x4){0.f, 0.f, 0.f, 0.f};

  // staging decode
  int srow = lane >> 2, gslot = lane & 3;
  // frag-read decode
  int r15 = lane & 15, gh = lane >> 4;
  int gA = gh ^ ((r15 >> 1) & 3);
  const unsigned short* Aw = As + ((wv >> 1) * 64) * 32;
  const unsigned short* Bw = Bs + ((wv & 1) * 64) * 32;

  for (int kt = 0; kt < 10; kt++) {
    int k0 = kt * 32;
#pragma unroll
    for (int i = 0; i < 2; i++) {
      int chunk = wv * 2 + i;
      int row = chunk * 16 + srow;
      int gg = gslot ^ ((row >> 1) & 3);
      gload_lds16(A2 + (size_t)(m0 + row) * KPAD + k0 + gg * 8, As + chunk * 512);
      gload_lds16(B2 + (size_t)(vbase + row) * KPAD + k0 + gg * 8, Bs + chunk * 512);
    }
    __syncthreads();
    bf16x8 af[4], bf[4];
#pragma unroll
    for (int s = 0; s < 4; s++) {
      af[s] = *(const bf16x8*)(Aw + (s * 16 + r15) * 32 + gA * 8);
      bf[s] = *(const bf16x8*)(Bw + (s * 16 + r15) * 32 + gA * 8);
    }
#pragma unroll
    for (int si = 0; si < 4; si++)
#pragma unroll
      for (int sj = 0; sj < 4; sj++)
        acc[si][sj] = __builtin_amdgcn_mfma_f32_16x16x32_bf16(af[si], bf[sj], acc[si][sj], 0, 0, 0);
    __syncthreads();
  }

  int colbase = vbase + (wv & 1) * 64;
  if (!PASSB) {
    // Z[m] += sum_v exp(logit)
#pragma unroll
    for (int si = 0; si < 4; si++) {
#pragma unroll
      for (int r = 0; r < 4; r++) {
        float es = 0.f;
#pragma unroll
        for (int sj = 0; sj < 4; sj++) {
          int v = colbase + sj * 16 + r15;
          es += (v < VDIM) ? __expf(acc[si][sj][r]) : 0.f;
        }
        es += __shfl_xor(es, 1, 64); es += __shfl_xor(es, 2, 64);
        es += __shfl_xor(es, 4, 64); es += __shfl_xor(es, 8, 64);
        if (r15 == 0)
          atomicAdd(&Z[m0 + (wv >> 1) * 64 + si * 16 + gh * 4 + r], es);
      }
    }
  } else {
#pragma unroll
    for (int si = 0; si < 4; si++)
#pragma unroll
      for (int sj = 0; sj < 4; sj++)
#pragma unroll
        for (int r = 0; r < 4; r++) acc[si][sj][r] = __expf(acc[si][sj][r]);
    int t = (m0 + (wv >> 1) * 64) >> 6;
    int cnt = bcnt[t];
    float nacc = 0.f;
    for (int n = 0; n < cnt; n++) {
      int b = bucket[t * 128 + n];
      float4 wv4[4];
#pragma unroll
      for (int si = 0; si < 4; si++)
        wv4[si] = *(const float4*)(wgt + b * 64 + si * 16 + gh * 4);
#pragma unroll
      for (int sj = 0; sj < 4; sj++) {
        float local = 0.f;
#pragma unroll
        for (int si = 0; si < 4; si++)
          local += wv4[si].x * acc[si][sj][0] + wv4[si].y * acc[si][sj][1] +
                   wv4[si].z * acc[si][sj][2] + wv4[si].w * acc[si][sj][3];
        local += __shfl_xor(local, 16, 64);
        local += __shfl_xor(local, 32, 64);
        int v = colbase + sj * 16 + r15;
        if (lane < 16 && v < VDIM)
          nacc += bows[(size_t)b * VDIM + v] * __logf(local + EPSF);
      }
    }
    nacc = wred64(nacc);
    if (lane == 0) p[wv] = nacc;
    __syncthreads();
    if (tid == 0) atomicAdd(&scal[0], p[0] + p[1] + p[2] + p[3]);
  }
}

// ================= fallback-path MFMA kernels (round-1, known-good) =========
__device__ inline void stage_B(const float* __restrict__ we, int vbase,
                               unsigned short* LB, int tid) {
  for (int q = tid; q < VT * 75; q += 256) {
    int vp = q / 75, e4 = (q % 75) * 4;
    float4 w = *(const float4*)(we + (size_t)(vbase + vp) * EDIM + e4);
    unsigned* p32 = (unsigned*)(LB + vp * LBSTR + e4);
    p32[0] = (unsigned)f2bf(w.x) | ((unsigned)f2bf(w.y) << 16);
    p32[1] = (unsigned)f2bf(w.z) | ((unsigned)f2bf(w.w) << 16);
  }
  for (int q = tid; q < VT * 28; q += 256) {
    int vp = q / 28, e = 300 + q % 28;
    LB[vp * LBSTR + e] = 0;
  }
}

__device__ inline void quad_mainloop(const unsigned short* __restrict__ A2,
                                     const unsigned short* LB, int quad, int lane,
                                     f32x4 (&acc)[4][5]) {
  int mrow = quad * 64 + (lane & 15);
  int eoff = (lane >> 4) * 8;
  const bf16x8* ap[4];
#pragma unroll
  for (int ss = 0; ss < 4; ss++)
    ap[ss] = (const bf16x8*)(A2 + (size_t)(mrow + ss * 16) * KPAD + eoff);
  const unsigned short* bp = LB + (lane & 15) * LBSTR + eoff;
#pragma unroll
  for (int kk = 0; kk < 10; kk++) {
    bf16x8 a[4];
#pragma unroll
    for (int ss = 0; ss < 4; ss++) a[ss] = ap[ss][kk * 4];
#pragma unroll
    for (int cf = 0; cf < 5; cf++) {
      bf16x8 b = *(const bf16x8*)(bp + cf * 16 * LBSTR + kk * 32);
#pragma unroll
      for (int ss = 0; ss < 4; ss++)
        acc[ss][cf] = __builtin_amdgcn_mfma_f32_16x16x32_bf16(a[ss], b, acc[ss][cf], 0, 0, 0);
    }
  }
}

__global__ __launch_bounds__(256, 2) void k_passA(const float* __restrict__ we,
                                                  const unsigned short* __restrict__ A2,
                                                  float* __restrict__ Z) {
  __shared__ __align__(16) unsigned short LB[VT * LBSTR];
  int tid = threadIdx.x, vbase = blockIdx.x * VT;
  stage_B(we, vbase, LB, tid);
  __syncthreads();
  int wave = tid >> 6, lane = tid & 63;
  for (int q = wave; q < TDIM; q += 4) {
    f32x4 acc[4][5];
#pragma unroll
    for (int ss = 0; ss < 4; ss++)
#pragma unroll
      for (int cf = 0; cf < 5; cf++) acc[ss][cf] = (f32x4){0.f, 0.f, 0.f, 0.f};
    quad_mainloop(A2, LB, q, lane, acc);
#pragma unroll
    for (int ss = 0; ss < 4; ss++) {
#pragma unroll
      for (int r = 0; r < 4; r++) {
        float s = __expf(acc[ss][0][r]) + __expf(acc[ss][1][r]) + __expf(acc[ss][2][r]) +
                  __expf(acc[ss][3][r]) + __expf(acc[ss][4][r]);
        s += __shfl_xor(s, 1, 64); s += __shfl_xor(s, 2, 64);
        s += __shfl_xor(s, 4, 64); s += __shfl_xor(s, 8, 64);
        if ((lane & 15) == 0)
          atomicAdd(&Z[q * 64 + ss * 16 + (lane >> 4) * 4 + r], s);
      }
    }
  }
}

__global__ __launch_bounds__(256, 2) void k_passB(const float* __restrict__ we,
                                                  const unsigned short* __restrict__ A2,
                                                  const float* __restrict__ wgt,
                                                  const float* __restrict__ bows,
                                                  const int* __restrict__ bcnt,
                                                  const int* __restrict__ bucket,
                                                  float* __restrict__ scal) {
  __shared__ __align__(16) unsigned short LB[VT * LBSTR];
  int tid = threadIdx.x, vbase = blockIdx.x * VT;
  stage_B(we, vbase, LB, tid);
  __syncthreads();
  int wave = tid >> 6, lane = tid & 63;
  float nacc = 0.f;
  for (int t = wave; t < TDIM; t += 4) {
    f32x4 acc[4][5];
#pragma unroll
    for (int ss = 0; ss < 4; ss++)
#pragma unroll
      for (int cf = 0; cf < 5; cf++) acc[ss][cf] = (f32x4){0.f, 0.f, 0.f, 0.f};
    quad_mainloop(A2, LB, t, lane, acc);
#pragma unroll
    for (int ss = 0; ss < 4; ss++)
#pragma unroll
      for (int cf = 0; cf < 5; cf++)
#pragma unroll
        for (int r = 0; r < 4; r++) acc[ss][cf][r] = __expf(acc[ss][cf][r]);
    int cnt = bcnt[t];
    for (int n = 0; n < cnt; n++) {
      int b = bucket[t * 128 + n];
      float4 w[4];
#pragma unroll
      for (int ss = 0; ss < 4; ss++)
        w[ss] = *(const float4*)(wgt + b * 64 + ss * 16 + (lane >> 4) * 4);
#pragma unroll
      for (int cf = 0; cf < 5; cf++) {
        float local = 0.f;
#pragma unroll
        for (int ss = 0; ss < 4; ss++)
          local += w[ss].x * acc[ss][cf][0] + w[ss].y * acc[ss][cf][1] +
                   w[ss].z * acc[ss][cf][2] + w[ss].w * acc[ss][cf][3];
        local += __shfl_xor(local, 16, 64);
        local += __shfl_xor(local, 32, 64);
        int v = vbase + cf * 16 + (lane & 15);
        float contrib = bows[(size_t)b * VDIM + v] * __logf(local + EPSF);
        if (lane < 16) nacc += contrib;
      }
    }
  }
  nacc = wred64(nacc);
  __shared__ float p[4];
  if (lane == 0) p[wave] = nacc;
  __syncthreads();
  if (tid == 0) atomicAdd(&scal[0], p[0] + p[1] + p[2] + p[3]);
}

// ---------------- finalize ---------------------------------------------------
__global__ void k_finalize(const float* __restrict__ scal, float* __restrict__ out) {
  if (threadIdx.x == 0 && blockIdx.x == 0) {
    float nll = -scal[0];
    out[0] = nll + scal[1] + scal[2] + scal[3];
    out[1] = nll;
    out[2] = scal[1];
    out[3] = scal[2];
    out[4] = scal[3];
  }
}

extern "C" void kernel_launch(void* const* d_in, const int* in_sizes, int n_in,
                              void* d_out, int out_size, void* d_ws, size_t ws_size,
                              hipStream_t stream) {
  const float* bows  = (const float*)d_in[0];
  const float* nbows = (const float*)d_in[1];
  const float* rnn   = (const float*)d_in[2];
  const float* wemb  = (const float*)d_in[3];
  const float* mua   = (const float*)d_in[4];
  const float* lsa   = (const float*)d_in[5];
  const float* Wth   = (const float*)d_in[6];
  const float* bth   = (const float*)d_in[7];
  const float* Wmt   = (const float*)d_in[8];
  const float* bmt   = (const float*)d_in[9];
  const float* Wlt   = (const float*)d_in[10];
  const float* blt   = (const float*)d_in[11];
  const float* Wmap  = (const float*)d_in[12];
  const float* bmap  = (const float*)d_in[13];
  const float* Wih   = (const float*)d_in[14];
  const float* Whh   = (const float*)d_in[15];
  const float* bihp  = (const float*)d_in[16];
  const float* bhhp  = (const float*)d_in[17];
  const float* Wme   = (const float*)d_in[18];
  const float* bme   = (const float*)d_in[19];
  const float* Wle   = (const float*)d_in[20];
  const float* ble   = (const float*)d_in[21];
  const int* times   = (const int*)d_in[22];

  float* ws = (float*)d_ws;
  float* scal  = ws;                 // 8
  float* Z     = ws + 8;             // 2560
  float* hpre  = ws + 2568;          // 80000
  float* omap  = ws + 82568;         // 8000   (end of zeroed region: 90568 floats)
  float* xa    = ws + 90568;         // 8000
  float* xb    = ws + 98568;         // 8000
  float* lout  = ws + 106568;        // 8000
  float* Gin   = ws + 114568;        // 32000
  unsigned* WhhT = (unsigned*)(ws + 146568);   // 240000
  float* etas  = ws + 386568;        // 2000
  float* theta = ws + 388568;        // 5000
  float* wgt   = ws + 393568;        // 6400
  int* bcnt    = (int*)(ws + 399968);          // 64
  int* bucket  = (int*)(ws + 400032);          // 5120
  unsigned short* A2 = (unsigned short*)(ws + 405152);  // 819200 ushorts -> ends 814752
  unsigned short* B2 = (unsigned short*)(ws + 814752);  // 30080*320 ushorts = 19.25 MB

  // fast path needs ws up to byte offset 814752*4 + 19251200 = 22510208
  bool fast = ws_size >= 23000000u;

  hipMemsetAsync(ws, 0, 90568 * sizeof(float), stream);

  k_prep_A2<<<3200, 256, 0, stream>>>(mua, A2);
  if (fast) k_prep_B<<<9400, 256, 0, stream>>>(wemb, B2);
  k_map2<<<dim3(313, 2), 256, 0, stream>>>(rnn, Wmap, bmap, omap);
  k_wt<<<300, 256, 0, stream>>>(Whh, WhhT);
  k_bucket<<<1, 128, 0, stream>>>(times, bcnt, bucket);

  if (fast)
    k_gemm<false><<<dim3(235, 20), 256, 0, stream>>>(A2, B2, Z, nullptr, nullptr,
                                                     nullptr, nullptr, nullptr);
  else
    k_passA<<<NBLK_V, 256, 0, stream>>>(wemb, A2, Z);

  k_igemm<<<400, 256, 0, stream>>>(Wih, bihp, bhhp, omap, Gin, 0);
  k_rec<<<1, 1024, 0, stream>>>(WhhT, Gin, xa);
  k_igemm<<<400, 256, 0, stream>>>(Wih, bihp, bhhp, xa, Gin, 1);
  k_rec<<<1, 1024, 0, stream>>>(WhhT + 100 * 800, Gin, xb);
  k_igemm<<<400, 256, 0, stream>>>(Wih, bihp, bhhp, xb, Gin, 2);
  k_rec<<<1, 1024, 0, stream>>>(WhhT + 200 * 800, Gin, lout);

  k_eta<<<1, 512, 0, stream>>>(Wme, bme, Wle, ble, lout, etas, scal);
  k_hpre<<<dim3(7, 47), 256, 0, stream>>>(nbows, Wth, hpre);
  k_theta<<<100, 256, 0, stream>>>(hpre, bth, Wth, Wmt, bmt, Wlt, blt, etas, times, theta, scal);
  k_wgt<<<25, 256, 0, stream>>>(theta, Z, times, wgt);
  k_klalpha<<<2344, 256, 0, stream>>>(mua, lsa, scal);

  if (fast)
    k_gemm<true><<<dim3(235, 20), 256, 0, stream>>>(A2, B2, Z, wgt, bows, bcnt,
                                                    bucket, scal);
  else
    k_passB<<<NBLK_V, 256, 0, stream>>>(wemb, A2, wgt, bows, bcnt, bucket, scal);

  k_finalize<<<1, 64, 0, stream>>>(scal, (float*)d_out);
}